// Round 6
// baseline (11431.893 us; speedup 1.0000x reference)
//
#include <hip/hip_runtime.h>

#define SS 512
#define II 1024
#define HH 1024
#define NELEM (32 * SS * II)   // B*S*I elements of x

typedef short bf16x8 __attribute__((ext_vector_type(8)));
typedef float f32x4 __attribute__((ext_vector_type(4)));
typedef unsigned int u32;
typedef u32 u32x4 __attribute__((ext_vector_type(4)));

// ---- workspace byte layout ----
// [0, 512K)        hb: LLC tagged h ping-pong (2 slot x 2 dir x 32 x 1024 dw)
// [512K, +64)      cnt0: copier tickets (8 u32)          -- memset'd
// [528K]           epoch: persistent launch counter      -- NEVER memset
// [544K, +1K)      xflags: 8 xcd x 128B local flags      -- not memset (salted)
// [1M, 3M)         xcdbuf: 8 xcd x (2 slot x 2 dir x 32 x 512 dw packed)
// [3M, 3M+32M)     xb: bf16 x copy (full layout)
#define WS_CNT0    (512 * 1024)
#define WS_MEMLEN  (512 * 1024 + 64)
#define WS_EPOCH   (528 * 1024)
#define WS_XFLAGS  (544 * 1024)
#define WS_XCDBUF  (1024 * 1024)
#define WS_XB_FULL (3 * 1024 * 1024)
#define WS_XB_MID  (1024 * 1024)

__device__ __forceinline__ short f2bf_s(float f) {
    union { float fv; u32 i; } v; v.fv = f;
    u32 r = v.i + 0x7FFF + ((v.i >> 16) & 1);  // RNE
    return (short)(r >> 16);
}
__device__ __forceinline__ float sigm(float x)   { return 1.0f / (1.0f + __expf(-x)); }
__device__ __forceinline__ float tanh_f(float x) { return 2.0f / (1.0f + __expf(-2.0f * x)) - 1.0f; }

__device__ __forceinline__ bf16x8 cvt8(const float* p) {
    bf16x8 r;
#pragma unroll
    for (int j = 0; j < 8; ++j) r[j] = f2bf_s(p[j]);
    return r;
}

__global__ void __launch_bounds__(256)
cvt_x_kernel(const float* __restrict__ x, ushort* __restrict__ xb) {
    const int i = (blockIdx.x * 256 + threadIdx.x) * 8;
    *(bf16x8*)(xb + i) = cvt8(x + i);
}

#define A_ST(p, v) __hip_atomic_store((p), (v), __ATOMIC_RELAXED, __HIP_MEMORY_SCOPE_AGENT)

// LLC-coherent 16B load (bypass L1+L2) — tag-validated data
#define HLOADC(dst, base, OFF)                                             \
    asm volatile("global_load_dwordx4 %0, %1, off offset:" #OFF " sc0 sc1" \
                 : "=v"(dst) : "v"(base))
// XCD-local 16B load (bypass L1, served by this XCD's L2)
#define LLOAD(dst, base, OFF)                                        \
    asm volatile("global_load_dwordx4 %0, %1, off offset:" #OFF " sc0" \
                 : "=v"(dst) : "v"(base))
// XCD-local 16B store (write-through L1 -> lands in local L2)
#define LSTORE(src, base, OFF)                                        \
    asm volatile("global_store_dwordx4 %0, %1, off offset:" #OFF " sc0" \
                 :: "v"(base), "v"(src) : "memory")
// Full drain + scheduler fence (rule #18); robust vs compiler-inserted vmem
#define VMWAIT0() do {                                          \
    asm volatile("s_waitcnt vmcnt(0)" ::: "memory");            \
    __builtin_amdgcn_sched_barrier(0);                          \
} while (0)

// Remote (LLC) tagged row read + validate + pack: fallback path, and the
// correctness anchor for odd block placements. Expects tag == t.
#define REMOTE_ROW(H4, BASE) do {                                          \
    u32x4 tmp[16];                                                         \
    for (int tr_ = 0; tr_ < 4096; ++tr_) {                                 \
        HLOADC(tmp[0],  BASE, 0);   HLOADC(tmp[1],  BASE, 16);             \
        HLOADC(tmp[2],  BASE, 128); HLOADC(tmp[3],  BASE, 144);            \
        HLOADC(tmp[4],  BASE, 256); HLOADC(tmp[5],  BASE, 272);            \
        HLOADC(tmp[6],  BASE, 384); HLOADC(tmp[7],  BASE, 400);            \
        HLOADC(tmp[8],  BASE, 512); HLOADC(tmp[9],  BASE, 528);            \
        HLOADC(tmp[10], BASE, 640); HLOADC(tmp[11], BASE, 656);            \
        HLOADC(tmp[12], BASE, 768); HLOADC(tmp[13], BASE, 784);            \
        HLOADC(tmp[14], BASE, 896); HLOADC(tmp[15], BASE, 912);            \
        VMWAIT0();                                                         \
        u32 dv_ = 0;                                                       \
        _Pragma("unroll")                                                  \
        for (int i_ = 0; i_ < 16; ++i_)                                    \
            _Pragma("unroll")                                              \
            for (int j_ = 0; j_ < 4; ++j_) dv_ |= (tmp[i_][j_] >> 16) ^ (u32)t; \
        if (__all(dv_ == 0)) break;                                        \
        __builtin_amdgcn_s_sleep(2);                                       \
    }                                                                      \
    _Pragma("unroll")                                                      \
    for (int it_ = 0; it_ < 8; ++it_) {                                    \
        H4[it_][0] = (tmp[2*it_][0]   & 0xffffu) | (tmp[2*it_][1]   << 16); \
        H4[it_][1] = (tmp[2*it_][2]   & 0xffffu) | (tmp[2*it_][3]   << 16); \
        H4[it_][2] = (tmp[2*it_+1][0] & 0xffffu) | (tmp[2*it_+1][1] << 16); \
        H4[it_][3] = (tmp[2*it_+1][2] & 0xffffu) | (tmp[2*it_+1][3] << 16); \
    }                                                                      \
} while (0)

// Persistent BiLSTM with XCD-LOCAL h broadcast tree.
// r2/r5 post-mortem: h exchange is coherent-fabric BW-bound (16MB/step ->
// 7.9us; 32MB/step -> 12.3us; ~2.6TB/s ceiling). This round: producers
// publish tagged h to LLC ONCE (256KB/step, fire-and-forget, tag<<16|bf16
// per dword => ack-free); per XCD, 8 fixed copier blocks (ticket once via
// atomicAdd; XCD from s_getreg XCC_ID) validate one 32KB segment, strip
// tags, store PACKED into an XCD-local buffer (lines stay in that XCD's
// L2), then set an epoch-salted local flag after a cheap LOCAL vmcnt ack.
// Consumers poll local flags (~0.15us) and read 64KB packed from local L2
// (4.3TB/s/XCD) instead of the LLC. Coherent traffic drops 16MB -> 2MB/step.
// Safety: slot overwrite at t+2 is transitively gated through copier flags
// and consumer publications (producer can't publish t+1 before consuming t,
// which needs its XCD's copiers done with t, which needs all t-1 consumers
// published...). Epoch salt (persistent cell outside memset, ++ by block 0
// after its loop — which cannot complete before all blocks started) kills
// cross-launch stale-L2-line hazards on xcdbuf/xflags. Consumers falling
// past 64 flag polls use the proven direct-LLC tagged path (placement
// pathologies degrade speed, never correctness).
template <int USE_XB>
__global__ void __launch_bounds__(256, 1)
bilstm_persist(const float* __restrict__ x,
               const float* __restrict__ Wii_f, const float* __restrict__ Whi_f,
               const float* __restrict__ bi_f,
               const float* __restrict__ Wii_r, const float* __restrict__ Whi_r,
               const float* __restrict__ bi_r,
               float* __restrict__ out, u32* __restrict__ hb,
               const ushort* __restrict__ xb,
               u32* __restrict__ xcdbuf, u32* __restrict__ xflags,
               u32* __restrict__ cnt0, u32* __restrict__ epoch,
               const int useloc)
{
    const int g   = blockIdx.x;
    const int d   = g >> 7;
    const int u0  = (g & 127) * 8;
    const int tid = threadIdx.x;
    const int w   = tid >> 6;
    const int l   = tid & 63;
    const int q   = l >> 4;
    const int ln  = l & 15;
    const int kw  = w * 256;

    // physical XCD id (stable for the lifetime of this persistent block)
    u32 xcc;
    asm volatile("s_getreg_b32 %0, hwreg(HW_REG_XCC_ID)" : "=s"(xcc));
    xcc &= 7;

    // launch epoch (read by ALL blocks before block 0 can possibly finish)
    u32 E;
    asm volatile("global_load_dword %0, %1, off sc0 sc1" : "=v"(E) : "v"(epoch));
    VMWAIT0();
    const u32 fsalt = E << 9;   // local-flag salt; t fits in 9 bits

    // one-time copier election: first 8 blocks (ticket) on each XCD
    __shared__ u32 sh_tk;
    if (tid == 0)
        sh_tk = useloc ? __hip_atomic_fetch_add(cnt0 + xcc, 1u, __ATOMIC_RELAXED,
                                                __HIP_MEMORY_SCOPE_AGENT)
                       : 0xffffu;
    __syncthreads();
    const u32 tk = sh_tk;
    const int is_cop = (tk < 8);
    const int seg = (int)(tk & 7);          // segment: dir = seg>>2, rowgroup = seg&3

    const float* Wx = d ? Wii_r : Wii_f;
    const float* Wh = d ? Whi_r : Whi_f;
    const float* bi = d ? bi_r  : bi_f;

    // Weight fragments: B-frag lane holds B[k=q*8+j][n=ln] = W[col n][k]
    bf16x8 wx[8][2], wh[8][2];
#pragma unroll
    for (int nt = 0; nt < 2; ++nt) {
        const int n = nt * 16 + ln;                    // local gate-col 0..31
        const int r = (n >> 3) * HH + u0 + (n & 7);    // W row: gate*H + unit
#pragma unroll
        for (int it = 0; it < 8; ++it) {
            const int off = r * 1024 + kw + it * 32 + q * 8;
            wx[it][nt] = cvt8(Wx + off);
            wh[it][nt] = cvt8(Wh + off);
        }
    }

    const int eb = tid >> 3;   // batch 0..31
    const int eu = tid & 7;    // local unit 0..7
    float bias[4];
#pragma unroll
    for (int gate = 0; gate < 4; ++gate)
        bias[gate] = bi[gate * HH + u0 + eu];

    float c_state = 0.0f;
    __shared__ float part[2][4][32][33];   // double-buffered by t&1
    const f32x4 zero4 = {0.0f, 0.0f, 0.0f, 0.0f};

    for (int t = 0; t < SS; ++t) {
        const int tx = d ? (SS - 1 - t) : t;
        const int s  = (t - 1) & 1;        // read slot (valid for t>0)
        u32* hwp = hb + (size_t)((t & 1) * 2 + d) * 32 * 1024;

        f32x4 acc[2][2];
        acc[0][0] = zero4; acc[0][1] = zero4; acc[1][0] = zero4; acc[1][1] = zero4;

        // ---- phase A (copiers only): validate + strip + localize one segment
        if (t > 0 && is_cop) {
            const int cds  = seg >> 2;
            const int crow = (seg & 3) * 8 + (tid >> 5);
            const int ccol = (tid & 31) * 32;
            const u32* sb = hb + ((size_t)(s * 2 + cds) * 32 + crow) * 1024 + ccol;
            u32x4 cv[8];
            for (int tr = 0; tr < (1 << 16); ++tr) {
                HLOADC(cv[0], sb, 0);  HLOADC(cv[1], sb, 16);
                HLOADC(cv[2], sb, 32); HLOADC(cv[3], sb, 48);
                HLOADC(cv[4], sb, 64); HLOADC(cv[5], sb, 80);
                HLOADC(cv[6], sb, 96); HLOADC(cv[7], sb, 112);
                VMWAIT0();
                u32 dv = 0;
#pragma unroll
                for (int i = 0; i < 8; ++i)
#pragma unroll
                    for (int j = 0; j < 4; ++j) dv |= (cv[i][j] >> 16) ^ (u32)t;
                if (__all(dv == 0)) break;
                __builtin_amdgcn_s_sleep(2);
            }
            u32x4 pk[4];
#pragma unroll
            for (int k2 = 0; k2 < 4; ++k2)
#pragma unroll
                for (int e = 0; e < 4; ++e) {
                    const int j = k2 * 4 + e;
                    pk[k2][e] = (cv[j >> 1][2 * (j & 1)] & 0xffffu) |
                                (cv[j >> 1][2 * (j & 1) + 1] << 16);
                }
            u32* db = xcdbuf + ((size_t)((xcc * 2 + s) * 2 + cds) * 32 + crow) * 512
                             + (ccol >> 1);
            LSTORE(pk[0], db, 0);  LSTORE(pk[1], db, 16);
            LSTORE(pk[2], db, 32); LSTORE(pk[3], db, 48);
            VMWAIT0();                         // local L2 ack (cheap)
            __builtin_amdgcn_s_barrier();      // whole block's segment stored
            if (tid == 0) {
                u32* fp = xflags + xcc * 32 + s * 8 + seg;
                const u32 fv = fsalt | (u32)t;
                asm volatile("global_store_dword %0, %1, off sc0"
                             :: "v"(fp), "v"(fv) : "memory");
            }
        }

        // ---- phase B: x-MFMAs (compiler-scheduled loads; overlaps copies)
#pragma unroll
        for (int it = 0; it < 8; ++it) {
            const int ko = kw + it * 32 + q * 8;
            bf16x8 ax0, ax1;
            if (USE_XB) {
                ax0 = *(const bf16x8*)(xb + ((size_t)(ln * SS + tx)) * II + ko);
                ax1 = *(const bf16x8*)(xb + ((size_t)((16 + ln) * SS + tx)) * II + ko);
            } else {
                ax0 = cvt8(x + ((size_t)(ln * SS + tx)) * II + ko);
                ax1 = cvt8(x + ((size_t)((16 + ln) * SS + tx)) * II + ko);
            }
            acc[0][0] = __builtin_amdgcn_mfma_f32_16x16x32_bf16(ax0, wx[it][0], acc[0][0], 0, 0, 0);
            acc[0][1] = __builtin_amdgcn_mfma_f32_16x16x32_bf16(ax0, wx[it][1], acc[0][1], 0, 0, 0);
            acc[1][0] = __builtin_amdgcn_mfma_f32_16x16x32_bf16(ax1, wx[it][0], acc[1][0], 0, 0, 0);
            acc[1][1] = __builtin_amdgcn_mfma_f32_16x16x32_bf16(ax1, wx[it][1], acc[1][1], 0, 0, 0);
        }

        // ---- phase C: consume h (local fast path / remote fallback)
        if (t > 0) {
            u32x4 h4a[8], h4b[8];              // packed h, rows ln / ln+16
            int gotlocal = 0;
            if (useloc) {
                const u32* fa = xflags + xcc * 32 + s * 8;
                const u32 want = fsalt | (u32)t;
                for (int ps = 0; ps < 64; ++ps) {
                    u32x4 f0, f1;
                    asm volatile("global_load_dwordx4 %0, %2, off sc0\n\t"
                                 "global_load_dwordx4 %1, %2, off offset:16 sc0"
                                 : "=v"(f0), "=v"(f1) : "v"(fa));
                    VMWAIT0();
                    if (f0[0] == want && f0[1] == want && f0[2] == want && f0[3] == want &&
                        f1[0] == want && f1[1] == want && f1[2] == want && f1[3] == want) {
                        gotlocal = 1; break;
                    }
                    __builtin_amdgcn_s_sleep(2);
                }
            }
            if (gotlocal) {
                const u32* lb0 = xcdbuf + ((size_t)((xcc * 2 + s) * 2 + d) * 32 + ln) * 512
                                        + (kw >> 1) + q * 4;
                const u32* lb1 = lb0 + 16 * 512;
                LLOAD(h4a[0], lb0, 0);   LLOAD(h4a[1], lb0, 64);
                LLOAD(h4a[2], lb0, 128); LLOAD(h4a[3], lb0, 192);
                LLOAD(h4a[4], lb0, 256); LLOAD(h4a[5], lb0, 320);
                LLOAD(h4a[6], lb0, 384); LLOAD(h4a[7], lb0, 448);
                LLOAD(h4b[0], lb1, 0);   LLOAD(h4b[1], lb1, 64);
                LLOAD(h4b[2], lb1, 128); LLOAD(h4b[3], lb1, 192);
                LLOAD(h4b[4], lb1, 256); LLOAD(h4b[5], lb1, 320);
                LLOAD(h4b[6], lb1, 384); LLOAD(h4b[7], lb1, 448);
                VMWAIT0();
            } else {
                const u32* rb0 = hb + ((size_t)(s * 2 + d) * 32 + ln) * 1024 + kw + q * 8;
                const u32* rb1 = rb0 + 16 * 1024;
                REMOTE_ROW(h4a, rb0);
                REMOTE_ROW(h4b, rb1);
            }
#pragma unroll
            for (int it = 0; it < 8; ++it) {
                const bf16x8 ah0 = __builtin_bit_cast(bf16x8, h4a[it]);
                const bf16x8 ah1 = __builtin_bit_cast(bf16x8, h4b[it]);
                acc[0][0] = __builtin_amdgcn_mfma_f32_16x16x32_bf16(ah0, wh[it][0], acc[0][0], 0, 0, 0);
                acc[0][1] = __builtin_amdgcn_mfma_f32_16x16x32_bf16(ah0, wh[it][1], acc[0][1], 0, 0, 0);
                acc[1][0] = __builtin_amdgcn_mfma_f32_16x16x32_bf16(ah1, wh[it][0], acc[1][0], 0, 0, 0);
                acc[1][1] = __builtin_amdgcn_mfma_f32_16x16x32_bf16(ah1, wh[it][1], acc[1][1], 0, 0, 0);
            }
        }

        // ---- phase D: reduce, gates, publish
        {
            float (*pb)[32][33] = part[t & 1];
#pragma unroll
            for (int mt = 0; mt < 2; ++mt)
#pragma unroll
                for (int nt = 0; nt < 2; ++nt)
#pragma unroll
                    for (int r4 = 0; r4 < 4; ++r4)
                        pb[w][mt * 16 + q * 4 + r4][nt * 16 + ln] = acc[mt][nt][r4];
        }
        asm volatile("s_waitcnt lgkmcnt(0)" ::: "memory");
        __builtin_amdgcn_s_barrier();
        __builtin_amdgcn_sched_barrier(0);
        asm volatile("" ::: "memory");

        float gi[4];
        {
            float (*pb)[32][33] = part[t & 1];
#pragma unroll
            for (int gate = 0; gate < 4; ++gate) {
                float s2 = bias[gate];
#pragma unroll
                for (int w2 = 0; w2 < 4; ++w2) s2 += pb[w2][eb][gate * 8 + eu];
                gi[gate] = s2;
            }
        }
        const float igate = sigm(gi[0]);
        const float fgate = sigm(gi[1]);
        const float ggate = tanh_f(gi[2]);
        const float ogate = sigm(gi[3]);
        c_state = fgate * c_state + igate * ggate;
        const float hv = ogate * tanh_f(c_state);

        // fire-and-forget tagged publish (tag = t+1 in the data dword)
        const u32 tagv = ((u32)(t + 1) << 16) | (u32)(unsigned short)f2bf_s(hv);
        A_ST(hwp + eb * 1024 + u0 + eu, tagv);
        out[((size_t)(eb * SS + tx)) * (2 * HH) + d * HH + u0 + eu] = hv;
    }

    // bump launch epoch (block 0 cannot get here before every block read it)
    if (g == 0 && tid == 0)
        __hip_atomic_fetch_add(epoch, 1u, __ATOMIC_RELAXED, __HIP_MEMORY_SCOPE_AGENT);
}

extern "C" void kernel_launch(void* const* d_in, const int* in_sizes, int n_in,
                              void* d_out, int out_size, void* d_ws, size_t ws_size,
                              hipStream_t stream)
{
    const float* x    = (const float*)d_in[0];
    const float* Wii  = (const float*)d_in[1];
    const float* Whi  = (const float*)d_in[2];
    const float* bi   = (const float*)d_in[3];
    const float* WiiR = (const float*)d_in[4];
    const float* WhiR = (const float*)d_in[5];
    const float* biR  = (const float*)d_in[6];
    float* out = (float*)d_out;

    u32* hb     = (u32*)d_ws;
    u32* cnt0   = (u32*)((char*)d_ws + WS_CNT0);
    u32* epoch  = (u32*)((char*)d_ws + WS_EPOCH);
    u32* xflags = (u32*)((char*)d_ws + WS_XFLAGS);
    u32* xcdbuf = (u32*)((char*)d_ws + WS_XCDBUF);

    const size_t need_full = (size_t)WS_XB_FULL + (size_t)NELEM * 2;
    const size_t need_mid  = (size_t)WS_XB_MID  + (size_t)NELEM * 2;

    hipMemsetAsync(d_ws, 0, WS_MEMLEN, stream);   // LLC tags + tickets only

    if (ws_size >= need_full) {
        ushort* xb = (ushort*)((char*)d_ws + WS_XB_FULL);
        hipLaunchKernelGGL(cvt_x_kernel, dim3(NELEM / (256 * 8)), dim3(256), 0, stream, x, xb);
        hipLaunchKernelGGL((bilstm_persist<1>), dim3(256), dim3(256), 0, stream,
                           x, Wii, Whi, bi, WiiR, WhiR, biR, out, hb, xb,
                           xcdbuf, xflags, cnt0, epoch, 1);
    } else if (ws_size >= need_mid) {
        // not enough room for xcdbuf+xb: remote-only (round-5 behavior)
        ushort* xb = (ushort*)((char*)d_ws + WS_XB_MID);
        hipLaunchKernelGGL(cvt_x_kernel, dim3(NELEM / (256 * 8)), dim3(256), 0, stream, x, xb);
        hipLaunchKernelGGL((bilstm_persist<1>), dim3(256), dim3(256), 0, stream,
                           x, Wii, Whi, bi, WiiR, WhiR, biR, out, hb, xb,
                           xcdbuf, xflags, cnt0, epoch, 0);
    } else {
        const int loc = (ws_size >= (size_t)WS_XCDBUF + 2 * 1024 * 1024) ? 1 : 0;
        hipLaunchKernelGGL((bilstm_persist<0>), dim3(256), dim3(256), 0, stream,
                           x, Wii, Whi, bi, WiiR, WhiR, biR, out, hb, (const ushort*)0,
                           xcdbuf, xflags, cnt0, epoch, loc);
    }
}